// Round 4
// baseline (267.987 us; speedup 1.0000x reference)
//
#include <hip/hip_runtime.h>

#define TPB 256
#define PROWS 32

typedef unsigned int uint32;
typedef unsigned short ushort16;

// ---------------------------------------------------------------------------
// helpers
// ---------------------------------------------------------------------------
__device__ __forceinline__ unsigned short f2bf(float f) {
  union { float f; unsigned int i; } c; c.f = f;
  unsigned int r = c.i + 0x7fffu + ((c.i >> 16) & 1u);   // RNE
  return (unsigned short)(r >> 16);
}

__device__ __forceinline__ float bflo(uint32 p) {   // low bf16 of packed pair
  union { unsigned int i; float f; } c; c.i = p << 16; return c.f;
}
__device__ __forceinline__ float bfhi(uint32 p) {   // high bf16 of packed pair
  union { unsigned int i; float f; } c; c.i = p & 0xffff0000u; return c.f;
}

// ---------------------------------------------------------------------------
// graph preprocessing: degrees, norm, CSR-by-dst (col only; norm folded into zws)
// ---------------------------------------------------------------------------
__global__ void count_deg_kernel(const int* __restrict__ dst, int E, int* __restrict__ deg) {
  int i = blockIdx.x * blockDim.x + threadIdx.x;
  if (i < E) atomicAdd(&deg[dst[i]], 1);
}

__global__ void dinv_kernel(const int* __restrict__ deg, int n, float* __restrict__ dinv) {
  int i = blockIdx.x * blockDim.x + threadIdx.x;
  if (i < n) dinv[i] = 1.0f / sqrtf((float)(deg[i] + 1));  // +1 self-loop
}

// block-wise exclusive scan; also emits per-block total
__global__ void scan_block_kernel(const int* __restrict__ in, int n,
                                  int* __restrict__ out_excl, int* __restrict__ bsum) {
  __shared__ int sh[TPB];
  int t = threadIdx.x;
  int i = blockIdx.x * TPB + t;
  int v = (i < n) ? in[i] : 0;
  sh[t] = v;
  __syncthreads();
  for (int off = 1; off < TPB; off <<= 1) {
    int x = (t >= off) ? sh[t - off] : 0;
    __syncthreads();
    sh[t] += x;
    __syncthreads();
  }
  if (i < n) out_excl[i] = sh[t] - v;          // exclusive
  if (t == TPB - 1 && bsum != nullptr) bsum[blockIdx.x] = sh[t];
}

__global__ void scan_fixup_kernel(int* __restrict__ rs, const int* __restrict__ boff,
                                  int n, int total) {
  int i = blockIdx.x * TPB + threadIdx.x;
  if (i < n) rs[i] += boff[blockIdx.x];
  else if (i == n) rs[n] = total;
}

// cursor[i] = rs[i]  (coalesced seed so fill needs no rs gather)
__global__ void seed_cursor_kernel(const int* __restrict__ rs, int* __restrict__ cursor, int n) {
  int i = blockIdx.x * blockDim.x + threadIdx.x;
  if (i < n) cursor[i] = rs[i];
}

__global__ void fill_kernel(const int* __restrict__ src, const int* __restrict__ dst, int E,
                            int* __restrict__ cursor, int* __restrict__ col) {
  int i = blockIdx.x * blockDim.x + threadIdx.x;
  if (i < E) {
    int s = src[i], d = dst[i];
    int p = atomicAdd(&cursor[d], 1);
    col[p] = s;
  }
}

// ---------------------------------------------------------------------------
// GEMM: zws[N,128](bf16) = dinv[r] * (A[N,128](f32) @ W[128,128](f32))
// ---------------------------------------------------------------------------
__global__ __launch_bounds__(256) void gemm128_kernel(const float* __restrict__ A,
                                                      const float* __restrict__ W,
                                                      const float* __restrict__ dinv,
                                                      ushort16* __restrict__ out, int nrows) {
  __shared__ float Wl[128 * 128];   // 64 KB
  __shared__ float Al[32][128];     // 16 KB
  int t = threadIdx.x;
  {
    const float4* __restrict__ W4 = (const float4*)W;
    float4* Wl4 = (float4*)Wl;
#pragma unroll
    for (int i = 0; i < 16; ++i) Wl4[t + 256 * i] = W4[t + 256 * i];
  }
  int r0 = blockIdx.x * 32;
  {
    const float4* __restrict__ A4 = (const float4*)A;
#pragma unroll
    for (int i = 0; i < 4; ++i) {
      int idx = t + 256 * i;        // 0..1023
      int r = idx >> 5;             // 0..31
      int cc = idx & 31;            // float4 index within row
      float4 v = make_float4(0.f, 0.f, 0.f, 0.f);
      if (r0 + r < nrows) v = A4[(size_t)(r0 + r) * 32 + cc];
      *(float4*)&Al[r][cc * 4] = v;
    }
  }
  __syncthreads();

  int c4 = (t & 31) * 4;            // output cols c4..c4+3
  int rg = (t >> 5) * 4;            // output rows rg..rg+3 (local)
  float4 acc0 = {0, 0, 0, 0}, acc1 = {0, 0, 0, 0}, acc2 = {0, 0, 0, 0}, acc3 = {0, 0, 0, 0};
#pragma unroll 8
  for (int k = 0; k < 128; ++k) {
    float4 w = *(const float4*)&Wl[k * 128 + c4];
    float a0 = Al[rg + 0][k];
    float a1 = Al[rg + 1][k];
    float a2 = Al[rg + 2][k];
    float a3 = Al[rg + 3][k];
    acc0.x += w.x * a0; acc0.y += w.y * a0; acc0.z += w.z * a0; acc0.w += w.w * a0;
    acc1.x += w.x * a1; acc1.y += w.y * a1; acc1.z += w.z * a1; acc1.w += w.w * a1;
    acc2.x += w.x * a2; acc2.y += w.y * a2; acc2.z += w.z * a2; acc2.w += w.w * a2;
    acc3.x += w.x * a3; acc3.y += w.y * a3; acc3.z += w.z * a3; acc3.w += w.w * a3;
  }
  int r = r0 + rg;
#pragma unroll
  for (int rr = 0; rr < 4; ++rr) {
    float4 acc = (rr == 0) ? acc0 : (rr == 1) ? acc1 : (rr == 2) ? acc2 : acc3;
    if (r + rr < nrows) {
      float di = dinv[r + rr];
      ushort4 p;
      p.x = f2bf(di * acc.x); p.y = f2bf(di * acc.y);
      p.z = f2bf(di * acc.z); p.w = f2bf(di * acc.w);
      *(ushort4*)&out[(size_t)(r + rr) * 128 + c4] = p;
    }
  }
}

// ---------------------------------------------------------------------------
// aggregation: out[n] = prelu( dinv[n]*( zws[n] + sum_{e: dst=n} zws[col[e]] ) + b )
// one wave (64 lanes) per node; each lane owns 2 of 128 columns (bf16 pair)
// ---------------------------------------------------------------------------
__global__ __launch_bounds__(256) void aggregate_kernel(
    const ushort16* __restrict__ zws, const int* __restrict__ rs,
    const int* __restrict__ col,
    const float* __restrict__ dinv, const float* __restrict__ bias,
    const float* __restrict__ alpha, float* __restrict__ out, int nrows) {
  int wid = threadIdx.x >> 6;
  int lane = threadIdx.x & 63;
  int node = blockIdx.x * 4 + wid;
  if (node >= nrows) return;
  int c = lane * 2;

  uint32 pv = *(const uint32*)&zws[(size_t)node * 128 + c];
  float accx = bflo(pv), accy = bfhi(pv);

  int e0 = rs[node], e1 = rs[node + 1];
  int e = e0;
  for (; e + 8 <= e1; e += 8) {
    uint32 p0 = *(const uint32*)&zws[(size_t)col[e + 0] * 128 + c];
    uint32 p1 = *(const uint32*)&zws[(size_t)col[e + 1] * 128 + c];
    uint32 p2 = *(const uint32*)&zws[(size_t)col[e + 2] * 128 + c];
    uint32 p3 = *(const uint32*)&zws[(size_t)col[e + 3] * 128 + c];
    uint32 p4 = *(const uint32*)&zws[(size_t)col[e + 4] * 128 + c];
    uint32 p5 = *(const uint32*)&zws[(size_t)col[e + 5] * 128 + c];
    uint32 p6 = *(const uint32*)&zws[(size_t)col[e + 6] * 128 + c];
    uint32 p7 = *(const uint32*)&zws[(size_t)col[e + 7] * 128 + c];
    accx += bflo(p0) + bflo(p1) + bflo(p2) + bflo(p3)
          + bflo(p4) + bflo(p5) + bflo(p6) + bflo(p7);
    accy += bfhi(p0) + bfhi(p1) + bfhi(p2) + bfhi(p3)
          + bfhi(p4) + bfhi(p5) + bfhi(p6) + bfhi(p7);
  }
  for (; e < e1; ++e) {
    uint32 p0 = *(const uint32*)&zws[(size_t)col[e] * 128 + c];
    accx += bflo(p0);
    accy += bfhi(p0);
  }

  float di = dinv[node];
  float2 b = *(const float2*)&bias[c];
  float2 al = *(const float2*)&alpha[c];
  float zx = di * accx + b.x, zy = di * accy + b.y;
  zx = zx > 0.f ? zx : al.x * zx;
  zy = zy > 0.f ? zy : al.y * zy;
  float2 r; r.x = zx; r.y = zy;
  *(float2*)&out[(size_t)node * 128 + c] = r;
}

// ---------------------------------------------------------------------------
// pooling: g[gi] = [ sum_{batch[n]==gi} z1[n] | sum z2[n] ]  (batch sorted)
// chunked over nodes: block = PROWS rows, running segmented sum + atomicAdd
// at segment boundaries. g must be pre-zeroed.
// ---------------------------------------------------------------------------
__global__ __launch_bounds__(256) void pool_kernel(const float* __restrict__ z1,
                                                   const float* __restrict__ z2,
                                                   const int* __restrict__ batch, int n,
                                                   float* __restrict__ g) {
  int r0 = blockIdx.x * PROWS;
  int t = threadIdx.x;
  __shared__ int bsh[PROWS];
  int rmax = n - r0; if (rmax > PROWS) rmax = PROWS;
  if (t < PROWS && t < rmax) bsh[t] = batch[r0 + t];
  __syncthreads();

  int c = t & 127;
  const float* __restrict__ src = (t < 128) ? z1 : z2;
  float acc = 0.f;
  int cur = bsh[0];
  for (int i = 0; i < rmax; ++i) {
    int b = bsh[i];
    if (b != cur) {
      atomicAdd(&g[(size_t)cur * 256 + t], acc);
      acc = 0.f;
      cur = b;
    }
    acc += src[(size_t)(r0 + i) * 128 + c];
  }
  atomicAdd(&g[(size_t)cur * 256 + t], acc);
}

// ---------------------------------------------------------------------------
// launcher
// ---------------------------------------------------------------------------
extern "C" void kernel_launch(void* const* d_in, const int* in_sizes, int n_in,
                              void* d_out, int out_size, void* d_ws, size_t ws_size,
                              hipStream_t stream) {
  const float* x     = (const float*)d_in[0];
  const int*   ei    = (const int*)d_in[1];
  const int*   batch = (const int*)d_in[2];
  const float* W0    = (const float*)d_in[3];
  const float* b0    = (const float*)d_in[4];
  const float* a0    = (const float*)d_in[5];
  const float* W1    = (const float*)d_in[6];
  const float* b1    = (const float*)d_in[7];
  const float* a1    = (const float*)d_in[8];
  float* out = (float*)d_out;

  const int N = in_sizes[0] / 128;
  const int E = in_sizes[1] / 2;
  const int G = (out_size - N * 128) / 256;

  const int* src  = ei;       // edge_index[0]
  const int* dstp = ei + E;   // edge_index[1]

  // workspace layout (4-byte words)
  int* w = (int*)d_ws;
  size_t o = 0;
  int*      deg    = w + o; o += (size_t)N;
  int*      cursor = w + o; o += (size_t)N;
  int*      rs     = w + o; o += (size_t)((N + 1 + 3) & ~3);
  int*      bsum   = w + o; o += 256;
  int*      boff   = w + o; o += 256;
  int*      col    = w + o; o += (size_t)E;
  float*    dinv   = (float*)(w + o); o += (size_t)N;
  ushort16* zws    = (ushort16*)(w + o); o += (size_t)N * 64;   // bf16 [N,128]
  float*    z1     = (float*)(w + o); o += (size_t)N * 128;
  (void)ws_size; (void)n_in;

  const int blkE = (E + TPB - 1) / TPB;
  const int blkN = (N + TPB - 1) / TPB;   // also #scan blocks (<= 256 for N<=65536)

  float* g = out + (size_t)N * 128;

  // zero deg; zero pooled-output region
  hipMemsetAsync(deg, 0, (size_t)N * sizeof(int), stream);
  hipMemsetAsync(g, 0, (size_t)G * 256 * sizeof(float), stream);

  // degrees -> dinv
  count_deg_kernel<<<blkE, TPB, 0, stream>>>(dstp, E, deg);
  dinv_kernel<<<blkN, TPB, 0, stream>>>(deg, N, dinv);

  // exclusive scan of deg -> row_start (rs), hierarchical
  scan_block_kernel<<<blkN, TPB, 0, stream>>>(deg, N, rs, bsum);
  scan_block_kernel<<<1, TPB, 0, stream>>>(bsum, blkN, boff, nullptr);
  scan_fixup_kernel<<<(N + TPB) / TPB, TPB, 0, stream>>>(rs, boff, N, E);

  // seed cursors, CSR fill (col only)
  seed_cursor_kernel<<<blkN, TPB, 0, stream>>>(rs, cursor, N);
  fill_kernel<<<blkE, TPB, 0, stream>>>(src, dstp, E, cursor, col);

  // layer 0: zws = bf16(dinv * (x @ W0)) ; z1 = prelu(dinv*(zws_self + sum) + b0)
  gemm128_kernel<<<(N + 31) / 32, 256, 0, stream>>>(x, W0, dinv, zws, N);
  aggregate_kernel<<<(N + 3) / 4, 256, 0, stream>>>(zws, rs, col, dinv, b0, a0, z1, N);

  // layer 1
  gemm128_kernel<<<(N + 31) / 32, 256, 0, stream>>>(z1, W1, dinv, zws, N);
  aggregate_kernel<<<(N + 3) / 4, 256, 0, stream>>>(zws, rs, col, dinv, b1, a1, out, N);

  // pooling -> g
  pool_kernel<<<(N + PROWS - 1) / PROWS, 256, 0, stream>>>(z1, out, batch, N, g);
}

// Round 5
// 232.206 us; speedup vs baseline: 1.1541x; 1.1541x over previous
//
#include <hip/hip_runtime.h>

#define TPB 256
#define PROWS 32

typedef unsigned int uint32;
typedef unsigned short ushort16;

// ---------------------------------------------------------------------------
// helpers
// ---------------------------------------------------------------------------
__device__ __forceinline__ unsigned short f2bf(float f) {
  union { float f; unsigned int i; } c; c.f = f;
  unsigned int r = c.i + 0x7fffu + ((c.i >> 16) & 1u);   // RNE
  return (unsigned short)(r >> 16);
}

__device__ __forceinline__ float bflo(uint32 p) {   // low bf16 of packed pair
  union { unsigned int i; float f; } c; c.i = p << 16; return c.f;
}
__device__ __forceinline__ float bfhi(uint32 p) {   // high bf16 of packed pair
  union { unsigned int i; float f; } c; c.i = p & 0xffff0000u; return c.f;
}

// ---------------------------------------------------------------------------
// graph preprocessing: degrees + per-edge rank, norm, CSR-by-dst
// ---------------------------------------------------------------------------
// rank[i] = position of edge i within its dst bucket (and deg accumulates)
__global__ void count_rank_kernel(const int* __restrict__ dst, int E,
                                  int* __restrict__ deg, int* __restrict__ rank) {
  int i = blockIdx.x * blockDim.x + threadIdx.x;
  if (i < E) rank[i] = atomicAdd(&deg[dst[i]], 1);
}

__global__ void dinv_kernel(const int* __restrict__ deg, int n, float* __restrict__ dinv) {
  int i = blockIdx.x * blockDim.x + threadIdx.x;
  if (i < n) dinv[i] = 1.0f / sqrtf((float)(deg[i] + 1));  // +1 self-loop
}

// block-wise exclusive scan; also emits per-block total
__global__ void scan_block_kernel(const int* __restrict__ in, int n,
                                  int* __restrict__ out_excl, int* __restrict__ bsum) {
  __shared__ int sh[TPB];
  int t = threadIdx.x;
  int i = blockIdx.x * TPB + t;
  int v = (i < n) ? in[i] : 0;
  sh[t] = v;
  __syncthreads();
  for (int off = 1; off < TPB; off <<= 1) {
    int x = (t >= off) ? sh[t - off] : 0;
    __syncthreads();
    sh[t] += x;
    __syncthreads();
  }
  if (i < n) out_excl[i] = sh[t] - v;          // exclusive
  if (t == TPB - 1 && bsum != nullptr) bsum[blockIdx.x] = sh[t];
}

__global__ void scan_fixup_kernel(int* __restrict__ rs, const int* __restrict__ boff,
                                  int n, int total) {
  int i = blockIdx.x * TPB + threadIdx.x;
  if (i < n) rs[i] += boff[blockIdx.x];
  else if (i == n) rs[n] = total;
}

// atomic-free placement: col[rs[d] + rank[i]] = src[i]
__global__ void fill_kernel(const int* __restrict__ src, const int* __restrict__ dst,
                            const int* __restrict__ rank, const int* __restrict__ rs,
                            int E, int* __restrict__ col) {
  int i = blockIdx.x * blockDim.x + threadIdx.x;
  if (i < E) {
    int d = dst[i];
    col[rs[d] + rank[i]] = src[i];
  }
}

// ---------------------------------------------------------------------------
// GEMM: zws[N,128](bf16) = dinv[r] * (A[N,128](f32) @ W[128,128](f32))
// ---------------------------------------------------------------------------
__global__ __launch_bounds__(256) void gemm128_kernel(const float* __restrict__ A,
                                                      const float* __restrict__ W,
                                                      const float* __restrict__ dinv,
                                                      ushort16* __restrict__ out, int nrows) {
  __shared__ float Wl[128 * 128];   // 64 KB
  __shared__ float Al[32][128];     // 16 KB
  int t = threadIdx.x;
  {
    const float4* __restrict__ W4 = (const float4*)W;
    float4* Wl4 = (float4*)Wl;
#pragma unroll
    for (int i = 0; i < 16; ++i) Wl4[t + 256 * i] = W4[t + 256 * i];
  }
  int r0 = blockIdx.x * 32;
  {
    const float4* __restrict__ A4 = (const float4*)A;
#pragma unroll
    for (int i = 0; i < 4; ++i) {
      int idx = t + 256 * i;        // 0..1023
      int r = idx >> 5;             // 0..31
      int cc = idx & 31;            // float4 index within row
      float4 v = make_float4(0.f, 0.f, 0.f, 0.f);
      if (r0 + r < nrows) v = A4[(size_t)(r0 + r) * 32 + cc];
      *(float4*)&Al[r][cc * 4] = v;
    }
  }
  __syncthreads();

  int c4 = (t & 31) * 4;            // output cols c4..c4+3
  int rg = (t >> 5) * 4;            // output rows rg..rg+3 (local)
  float4 acc0 = {0, 0, 0, 0}, acc1 = {0, 0, 0, 0}, acc2 = {0, 0, 0, 0}, acc3 = {0, 0, 0, 0};
#pragma unroll 8
  for (int k = 0; k < 128; ++k) {
    float4 w = *(const float4*)&Wl[k * 128 + c4];
    float a0 = Al[rg + 0][k];
    float a1 = Al[rg + 1][k];
    float a2 = Al[rg + 2][k];
    float a3 = Al[rg + 3][k];
    acc0.x += w.x * a0; acc0.y += w.y * a0; acc0.z += w.z * a0; acc0.w += w.w * a0;
    acc1.x += w.x * a1; acc1.y += w.y * a1; acc1.z += w.z * a1; acc1.w += w.w * a1;
    acc2.x += w.x * a2; acc2.y += w.y * a2; acc2.z += w.z * a2; acc2.w += w.w * a2;
    acc3.x += w.x * a3; acc3.y += w.y * a3; acc3.z += w.z * a3; acc3.w += w.w * a3;
  }
  int r = r0 + rg;
#pragma unroll
  for (int rr = 0; rr < 4; ++rr) {
    float4 acc = (rr == 0) ? acc0 : (rr == 1) ? acc1 : (rr == 2) ? acc2 : acc3;
    if (r + rr < nrows) {
      float di = dinv[r + rr];
      ushort4 p;
      p.x = f2bf(di * acc.x); p.y = f2bf(di * acc.y);
      p.z = f2bf(di * acc.z); p.w = f2bf(di * acc.w);
      *(ushort4*)&out[(size_t)(r + rr) * 128 + c4] = p;
    }
  }
}

// ---------------------------------------------------------------------------
// aggregation: out[n] = prelu( dinv[n]*( zws[n] + sum_{e: dst=n} zws[col[e]] ) + b )
// one wave (64 lanes) per node; each lane owns 2 of 128 columns (bf16 pair)
// ---------------------------------------------------------------------------
__global__ __launch_bounds__(256) void aggregate_kernel(
    const ushort16* __restrict__ zws, const int* __restrict__ rs,
    const int* __restrict__ col,
    const float* __restrict__ dinv, const float* __restrict__ bias,
    const float* __restrict__ alpha, float* __restrict__ out, int nrows) {
  int wid = threadIdx.x >> 6;
  int lane = threadIdx.x & 63;
  int node = blockIdx.x * 4 + wid;
  if (node >= nrows) return;
  int c = lane * 2;

  uint32 pv = *(const uint32*)&zws[(size_t)node * 128 + c];
  float accx = bflo(pv), accy = bfhi(pv);

  int e0 = rs[node], e1 = rs[node + 1];
  int e = e0;
  for (; e + 8 <= e1; e += 8) {
    uint32 p0 = *(const uint32*)&zws[(size_t)col[e + 0] * 128 + c];
    uint32 p1 = *(const uint32*)&zws[(size_t)col[e + 1] * 128 + c];
    uint32 p2 = *(const uint32*)&zws[(size_t)col[e + 2] * 128 + c];
    uint32 p3 = *(const uint32*)&zws[(size_t)col[e + 3] * 128 + c];
    uint32 p4 = *(const uint32*)&zws[(size_t)col[e + 4] * 128 + c];
    uint32 p5 = *(const uint32*)&zws[(size_t)col[e + 5] * 128 + c];
    uint32 p6 = *(const uint32*)&zws[(size_t)col[e + 6] * 128 + c];
    uint32 p7 = *(const uint32*)&zws[(size_t)col[e + 7] * 128 + c];
    accx += bflo(p0) + bflo(p1) + bflo(p2) + bflo(p3)
          + bflo(p4) + bflo(p5) + bflo(p6) + bflo(p7);
    accy += bfhi(p0) + bfhi(p1) + bfhi(p2) + bfhi(p3)
          + bfhi(p4) + bfhi(p5) + bfhi(p6) + bfhi(p7);
  }
  for (; e < e1; ++e) {
    uint32 p0 = *(const uint32*)&zws[(size_t)col[e] * 128 + c];
    accx += bflo(p0);
    accy += bfhi(p0);
  }

  float di = dinv[node];
  float2 b = *(const float2*)&bias[c];
  float2 al = *(const float2*)&alpha[c];
  float zx = di * accx + b.x, zy = di * accy + b.y;
  zx = zx > 0.f ? zx : al.x * zx;
  zy = zy > 0.f ? zy : al.y * zy;
  float2 r; r.x = zx; r.y = zy;
  *(float2*)&out[(size_t)node * 128 + c] = r;
}

// ---------------------------------------------------------------------------
// pooling: g[gi] = [ sum_{batch[n]==gi} z1[n] | sum z2[n] ]  (batch sorted)
// chunked over nodes: block = PROWS rows, running segmented sum + atomicAdd
// at segment boundaries. g must be pre-zeroed.
// ---------------------------------------------------------------------------
__global__ __launch_bounds__(256) void pool_kernel(const float* __restrict__ z1,
                                                   const float* __restrict__ z2,
                                                   const int* __restrict__ batch, int n,
                                                   float* __restrict__ g) {
  int r0 = blockIdx.x * PROWS;
  int t = threadIdx.x;
  __shared__ int bsh[PROWS];
  int rmax = n - r0; if (rmax > PROWS) rmax = PROWS;
  if (t < PROWS && t < rmax) bsh[t] = batch[r0 + t];
  __syncthreads();

  int c = t & 127;
  const float* __restrict__ src = (t < 128) ? z1 : z2;
  float acc = 0.f;
  int cur = bsh[0];
  for (int i = 0; i < rmax; ++i) {
    int b = bsh[i];
    if (b != cur) {
      atomicAdd(&g[(size_t)cur * 256 + t], acc);
      acc = 0.f;
      cur = b;
    }
    acc += src[(size_t)(r0 + i) * 128 + c];
  }
  atomicAdd(&g[(size_t)cur * 256 + t], acc);
}

// ---------------------------------------------------------------------------
// launcher
// ---------------------------------------------------------------------------
extern "C" void kernel_launch(void* const* d_in, const int* in_sizes, int n_in,
                              void* d_out, int out_size, void* d_ws, size_t ws_size,
                              hipStream_t stream) {
  const float* x     = (const float*)d_in[0];
  const int*   ei    = (const int*)d_in[1];
  const int*   batch = (const int*)d_in[2];
  const float* W0    = (const float*)d_in[3];
  const float* b0    = (const float*)d_in[4];
  const float* a0    = (const float*)d_in[5];
  const float* W1    = (const float*)d_in[6];
  const float* b1    = (const float*)d_in[7];
  const float* a1    = (const float*)d_in[8];
  float* out = (float*)d_out;

  const int N = in_sizes[0] / 128;
  const int E = in_sizes[1] / 2;
  const int G = (out_size - N * 128) / 256;

  const int* src  = ei;       // edge_index[0]
  const int* dstp = ei + E;   // edge_index[1]

  // workspace layout (4-byte words)
  int* w = (int*)d_ws;
  size_t o = 0;
  int*      deg    = w + o; o += (size_t)N;
  int*      rs     = w + o; o += (size_t)((N + 1 + 3) & ~3);
  int*      bsum   = w + o; o += 256;
  int*      boff   = w + o; o += 256;
  int*      col    = w + o; o += (size_t)E;
  int*      rank   = w + o; o += (size_t)E;
  float*    dinv   = (float*)(w + o); o += (size_t)N;
  ushort16* zws    = (ushort16*)(w + o); o += (size_t)N * 64;   // bf16 [N,128]
  float*    z1     = (float*)(w + o); o += (size_t)N * 128;
  (void)ws_size; (void)n_in;

  const int blkE = (E + TPB - 1) / TPB;
  const int blkN = (N + TPB - 1) / TPB;   // also #scan blocks (<= 256 for N<=65536)

  float* g = out + (size_t)N * 128;

  // zero deg; zero pooled-output region
  hipMemsetAsync(deg, 0, (size_t)N * sizeof(int), stream);
  hipMemsetAsync(g, 0, (size_t)G * 256 * sizeof(float), stream);

  // degrees + per-edge rank -> dinv
  count_rank_kernel<<<blkE, TPB, 0, stream>>>(dstp, E, deg, rank);
  dinv_kernel<<<blkN, TPB, 0, stream>>>(deg, N, dinv);

  // exclusive scan of deg -> row_start (rs), hierarchical
  scan_block_kernel<<<blkN, TPB, 0, stream>>>(deg, N, rs, bsum);
  scan_block_kernel<<<1, TPB, 0, stream>>>(bsum, blkN, boff, nullptr);
  scan_fixup_kernel<<<(N + TPB) / TPB, TPB, 0, stream>>>(rs, boff, N, E);

  // CSR fill (atomic-free)
  fill_kernel<<<blkE, TPB, 0, stream>>>(src, dstp, rank, rs, E, col);

  // layer 0: zws = bf16(dinv * (x @ W0)) ; z1 = prelu(dinv*(zws_self + sum) + b0)
  gemm128_kernel<<<(N + 31) / 32, 256, 0, stream>>>(x, W0, dinv, zws, N);
  aggregate_kernel<<<(N + 3) / 4, 256, 0, stream>>>(zws, rs, col, dinv, b0, a0, z1, N);

  // layer 1
  gemm128_kernel<<<(N + 31) / 32, 256, 0, stream>>>(z1, W1, dinv, zws, N);
  aggregate_kernel<<<(N + 3) / 4, 256, 0, stream>>>(zws, rs, col, dinv, b1, a1, out, N);

  // pooling -> g
  pool_kernel<<<(N + PROWS - 1) / PROWS, 256, 0, stream>>>(z1, out, batch, N, g);
}

// Round 6
// 225.725 us; speedup vs baseline: 1.1872x; 1.0287x over previous
//
#include <hip/hip_runtime.h>

#define TPB 256
#define PROWS 32

typedef unsigned int uint32;
typedef unsigned short ushort16;

// ---------------------------------------------------------------------------
// helpers
// ---------------------------------------------------------------------------
__device__ __forceinline__ unsigned short f2bf(float f) {
  union { float f; unsigned int i; } c; c.f = f;
  unsigned int r = c.i + 0x7fffu + ((c.i >> 16) & 1u);   // RNE
  return (unsigned short)(r >> 16);
}

__device__ __forceinline__ float bflo(uint32 p) {   // low bf16 of packed pair
  union { unsigned int i; float f; } c; c.i = p << 16; return c.f;
}
__device__ __forceinline__ float bfhi(uint32 p) {   // high bf16 of packed pair
  union { unsigned int i; float f; } c; c.i = p & 0xffff0000u; return c.f;
}

// ---------------------------------------------------------------------------
// graph preprocessing: degrees + per-edge rank, norm, CSR-by-dst
// ---------------------------------------------------------------------------
__global__ void count_rank_kernel(const int* __restrict__ dst, int E,
                                  int* __restrict__ deg, int* __restrict__ rank) {
  int i = blockIdx.x * blockDim.x + threadIdx.x;
  if (i < E) rank[i] = atomicAdd(&deg[dst[i]], 1);
}

__global__ void dinv_kernel(const int* __restrict__ deg, int n, float* __restrict__ dinv) {
  int i = blockIdx.x * blockDim.x + threadIdx.x;
  if (i < n) dinv[i] = 1.0f / sqrtf((float)(deg[i] + 1));  // +1 self-loop
}

// block-wise exclusive scan; also emits per-block total
__global__ void scan_block_kernel(const int* __restrict__ in, int n,
                                  int* __restrict__ out_excl, int* __restrict__ bsum) {
  __shared__ int sh[TPB];
  int t = threadIdx.x;
  int i = blockIdx.x * TPB + t;
  int v = (i < n) ? in[i] : 0;
  sh[t] = v;
  __syncthreads();
  for (int off = 1; off < TPB; off <<= 1) {
    int x = (t >= off) ? sh[t - off] : 0;
    __syncthreads();
    sh[t] += x;
    __syncthreads();
  }
  if (i < n) out_excl[i] = sh[t] - v;          // exclusive
  if (t == TPB - 1 && bsum != nullptr) bsum[blockIdx.x] = sh[t];
}

__global__ void scan_fixup_kernel(int* __restrict__ rs, const int* __restrict__ boff,
                                  int n, int total) {
  int i = blockIdx.x * TPB + threadIdx.x;
  if (i < n) rs[i] += boff[blockIdx.x];
  else if (i == n) rs[n] = total;
}

// atomic-free placement: col[rs[d] + rank[i]] = src[i]
__global__ void fill_kernel(const int* __restrict__ src, const int* __restrict__ dst,
                            const int* __restrict__ rank, const int* __restrict__ rs,
                            int E, int* __restrict__ col) {
  int i = blockIdx.x * blockDim.x + threadIdx.x;
  if (i < E) {
    int d = dst[i];
    col[rs[d] + rank[i]] = src[i];
  }
}

// ---------------------------------------------------------------------------
// GEMM: zws[N,128](bf16) = dinv[r] * (A[N,128](f32) @ W[128,128](f32))
// ---------------------------------------------------------------------------
__global__ __launch_bounds__(256) void gemm128_kernel(const float* __restrict__ A,
                                                      const float* __restrict__ W,
                                                      const float* __restrict__ dinv,
                                                      ushort16* __restrict__ out, int nrows) {
  __shared__ float Wl[128 * 128];   // 64 KB
  __shared__ float Al[32][128];     // 16 KB
  int t = threadIdx.x;
  {
    const float4* __restrict__ W4 = (const float4*)W;
    float4* Wl4 = (float4*)Wl;
#pragma unroll
    for (int i = 0; i < 16; ++i) Wl4[t + 256 * i] = W4[t + 256 * i];
  }
  int r0 = blockIdx.x * 32;
  {
    const float4* __restrict__ A4 = (const float4*)A;
#pragma unroll
    for (int i = 0; i < 4; ++i) {
      int idx = t + 256 * i;        // 0..1023
      int r = idx >> 5;             // 0..31
      int cc = idx & 31;            // float4 index within row
      float4 v = make_float4(0.f, 0.f, 0.f, 0.f);
      if (r0 + r < nrows) v = A4[(size_t)(r0 + r) * 32 + cc];
      *(float4*)&Al[r][cc * 4] = v;
    }
  }
  __syncthreads();

  int c4 = (t & 31) * 4;            // output cols c4..c4+3
  int rg = (t >> 5) * 4;            // output rows rg..rg+3 (local)
  float4 acc0 = {0, 0, 0, 0}, acc1 = {0, 0, 0, 0}, acc2 = {0, 0, 0, 0}, acc3 = {0, 0, 0, 0};
#pragma unroll 8
  for (int k = 0; k < 128; ++k) {
    float4 w = *(const float4*)&Wl[k * 128 + c4];
    float a0 = Al[rg + 0][k];
    float a1 = Al[rg + 1][k];
    float a2 = Al[rg + 2][k];
    float a3 = Al[rg + 3][k];
    acc0.x += w.x * a0; acc0.y += w.y * a0; acc0.z += w.z * a0; acc0.w += w.w * a0;
    acc1.x += w.x * a1; acc1.y += w.y * a1; acc1.z += w.z * a1; acc1.w += w.w * a1;
    acc2.x += w.x * a2; acc2.y += w.y * a2; acc2.z += w.z * a2; acc2.w += w.w * a2;
    acc3.x += w.x * a3; acc3.y += w.y * a3; acc3.z += w.z * a3; acc3.w += w.w * a3;
  }
  int r = r0 + rg;
#pragma unroll
  for (int rr = 0; rr < 4; ++rr) {
    float4 acc = (rr == 0) ? acc0 : (rr == 1) ? acc1 : (rr == 2) ? acc2 : acc3;
    if (r + rr < nrows) {
      float di = dinv[r + rr];
      ushort4 p;
      p.x = f2bf(di * acc.x); p.y = f2bf(di * acc.y);
      p.z = f2bf(di * acc.z); p.w = f2bf(di * acc.w);
      *(ushort4*)&out[(size_t)(r + rr) * 128 + c4] = p;
    }
  }
}

// ---------------------------------------------------------------------------
// aggregation: out[n] = prelu( dinv[n]*( zws[n] + sum_{e: dst=n} zws[col[e]] ) + b )
// one wave per node. Wave-cooperative col staging: one coalesced load of up to
// 64 indices, broadcast via __shfl (readlane) -> all gathers independent.
// ---------------------------------------------------------------------------
__global__ __launch_bounds__(256) void aggregate_kernel(
    const ushort16* __restrict__ zws, const int* __restrict__ rs,
    const int* __restrict__ col,
    const float* __restrict__ dinv, const float* __restrict__ bias,
    const float* __restrict__ alpha, float* __restrict__ out, int nrows) {
  int wid = threadIdx.x >> 6;
  int lane = threadIdx.x & 63;
  int node = blockIdx.x * 4 + wid;
  if (node >= nrows) return;
  int c = lane * 2;

  uint32 pv = *(const uint32*)&zws[(size_t)node * 128 + c];
  float accx = bflo(pv), accy = bfhi(pv);

  int e0 = rs[node], e1 = rs[node + 1];
  for (int base = e0; base < e1; base += 64) {
    int nb = e1 - base; if (nb > 64) nb = 64;
    int colv = (base + lane < e1) ? col[base + lane] : 0;   // one coalesced load
    int j = 0;
    for (; j + 8 <= nb; j += 8) {
      int s0 = __shfl(colv, j + 0);
      int s1 = __shfl(colv, j + 1);
      int s2 = __shfl(colv, j + 2);
      int s3 = __shfl(colv, j + 3);
      int s4 = __shfl(colv, j + 4);
      int s5 = __shfl(colv, j + 5);
      int s6 = __shfl(colv, j + 6);
      int s7 = __shfl(colv, j + 7);
      uint32 p0 = *(const uint32*)&zws[(size_t)s0 * 128 + c];
      uint32 p1 = *(const uint32*)&zws[(size_t)s1 * 128 + c];
      uint32 p2 = *(const uint32*)&zws[(size_t)s2 * 128 + c];
      uint32 p3 = *(const uint32*)&zws[(size_t)s3 * 128 + c];
      uint32 p4 = *(const uint32*)&zws[(size_t)s4 * 128 + c];
      uint32 p5 = *(const uint32*)&zws[(size_t)s5 * 128 + c];
      uint32 p6 = *(const uint32*)&zws[(size_t)s6 * 128 + c];
      uint32 p7 = *(const uint32*)&zws[(size_t)s7 * 128 + c];
      accx += bflo(p0) + bflo(p1) + bflo(p2) + bflo(p3)
            + bflo(p4) + bflo(p5) + bflo(p6) + bflo(p7);
      accy += bfhi(p0) + bfhi(p1) + bfhi(p2) + bfhi(p3)
            + bfhi(p4) + bfhi(p5) + bfhi(p6) + bfhi(p7);
    }
    for (; j < nb; ++j) {
      int s = __shfl(colv, j);
      uint32 p = *(const uint32*)&zws[(size_t)s * 128 + c];
      accx += bflo(p);
      accy += bfhi(p);
    }
  }

  float di = dinv[node];
  float2 b = *(const float2*)&bias[c];
  float2 al = *(const float2*)&alpha[c];
  float zx = di * accx + b.x, zy = di * accy + b.y;
  zx = zx > 0.f ? zx : al.x * zx;
  zy = zy > 0.f ? zy : al.y * zy;
  float2 r; r.x = zx; r.y = zy;
  *(float2*)&out[(size_t)node * 128 + c] = r;
}

// ---------------------------------------------------------------------------
// pooling: g[gi] = [ sum_{batch[n]==gi} z1[n] | sum z2[n] ]  (batch sorted)
// chunked over nodes: block = PROWS rows, running segmented sum + atomicAdd
// at segment boundaries. g must be pre-zeroed.
// ---------------------------------------------------------------------------
__global__ __launch_bounds__(256) void pool_kernel(const float* __restrict__ z1,
                                                   const float* __restrict__ z2,
                                                   const int* __restrict__ batch, int n,
                                                   float* __restrict__ g) {
  int r0 = blockIdx.x * PROWS;
  int t = threadIdx.x;
  __shared__ int bsh[PROWS];
  int rmax = n - r0; if (rmax > PROWS) rmax = PROWS;
  if (t < PROWS && t < rmax) bsh[t] = batch[r0 + t];
  __syncthreads();

  int c = t & 127;
  const float* __restrict__ src = (t < 128) ? z1 : z2;
  float acc = 0.f;
  int cur = bsh[0];
  for (int i = 0; i < rmax; ++i) {
    int b = bsh[i];
    if (b != cur) {
      atomicAdd(&g[(size_t)cur * 256 + t], acc);
      acc = 0.f;
      cur = b;
    }
    acc += src[(size_t)(r0 + i) * 128 + c];
  }
  atomicAdd(&g[(size_t)cur * 256 + t], acc);
}

// ---------------------------------------------------------------------------
// launcher
// ---------------------------------------------------------------------------
extern "C" void kernel_launch(void* const* d_in, const int* in_sizes, int n_in,
                              void* d_out, int out_size, void* d_ws, size_t ws_size,
                              hipStream_t stream) {
  const float* x     = (const float*)d_in[0];
  const int*   ei    = (const int*)d_in[1];
  const int*   batch = (const int*)d_in[2];
  const float* W0    = (const float*)d_in[3];
  const float* b0    = (const float*)d_in[4];
  const float* a0    = (const float*)d_in[5];
  const float* W1    = (const float*)d_in[6];
  const float* b1    = (const float*)d_in[7];
  const float* a1    = (const float*)d_in[8];
  float* out = (float*)d_out;

  const int N = in_sizes[0] / 128;
  const int E = in_sizes[1] / 2;
  const int G = (out_size - N * 128) / 256;

  const int* src  = ei;       // edge_index[0]
  const int* dstp = ei + E;   // edge_index[1]

  // workspace layout (4-byte words)
  int* w = (int*)d_ws;
  size_t o = 0;
  int*      deg    = w + o; o += (size_t)N;
  int*      rs     = w + o; o += (size_t)((N + 1 + 3) & ~3);
  int*      bsum   = w + o; o += 256;
  int*      boff   = w + o; o += 256;
  int*      col    = w + o; o += (size_t)E;
  int*      rank   = w + o; o += (size_t)E;
  float*    dinv   = (float*)(w + o); o += (size_t)N;
  ushort16* zws    = (ushort16*)(w + o); o += (size_t)N * 64;   // bf16 [N,128]
  float*    z1     = (float*)(w + o); o += (size_t)N * 128;
  (void)ws_size; (void)n_in;

  const int blkE = (E + TPB - 1) / TPB;
  const int blkN = (N + TPB - 1) / TPB;   // also #scan blocks (<= 256 for N<=65536)

  float* g = out + (size_t)N * 128;

  // zero deg; zero pooled-output region
  hipMemsetAsync(deg, 0, (size_t)N * sizeof(int), stream);
  hipMemsetAsync(g, 0, (size_t)G * 256 * sizeof(float), stream);

  // degrees + per-edge rank -> dinv
  count_rank_kernel<<<blkE, TPB, 0, stream>>>(dstp, E, deg, rank);
  dinv_kernel<<<blkN, TPB, 0, stream>>>(deg, N, dinv);

  // exclusive scan of deg -> row_start (rs), hierarchical
  scan_block_kernel<<<blkN, TPB, 0, stream>>>(deg, N, rs, bsum);
  scan_block_kernel<<<1, TPB, 0, stream>>>(bsum, blkN, boff, nullptr);
  scan_fixup_kernel<<<(N + TPB) / TPB, TPB, 0, stream>>>(rs, boff, N, E);

  // CSR fill (atomic-free)
  fill_kernel<<<blkE, TPB, 0, stream>>>(src, dstp, rank, rs, E, col);

  // layer 0: zws = bf16(dinv * (x @ W0)) ; z1 = prelu(dinv*(zws_self + sum) + b0)
  gemm128_kernel<<<(N + 31) / 32, 256, 0, stream>>>(x, W0, dinv, zws, N);
  aggregate_kernel<<<(N + 3) / 4, 256, 0, stream>>>(zws, rs, col, dinv, b0, a0, z1, N);

  // layer 1
  gemm128_kernel<<<(N + 31) / 32, 256, 0, stream>>>(z1, W1, dinv, zws, N);
  aggregate_kernel<<<(N + 3) / 4, 256, 0, stream>>>(zws, rs, col, dinv, b1, a1, out, N);

  // pooling -> g
  pool_kernel<<<(N + PROWS - 1) / PROWS, 256, 0, stream>>>(z1, out, batch, N, g);
}

// Round 7
// 223.224 us; speedup vs baseline: 1.2005x; 1.0112x over previous
//
#include <hip/hip_runtime.h>

#define TPB 256
#define PROWS 32

typedef unsigned int uint32;
typedef unsigned short ushort16;

// ---------------------------------------------------------------------------
// helpers
// ---------------------------------------------------------------------------
__device__ __forceinline__ unsigned short f2bf(float f) {
  union { float f; unsigned int i; } c; c.f = f;
  unsigned int r = c.i + 0x7fffu + ((c.i >> 16) & 1u);   // RNE
  return (unsigned short)(r >> 16);
}

__device__ __forceinline__ float bflo(uint32 p) {   // low bf16 of packed pair
  union { unsigned int i; float f; } c; c.i = p << 16; return c.f;
}
__device__ __forceinline__ float bfhi(uint32 p) {   // high bf16 of packed pair
  union { unsigned int i; float f; } c; c.i = p & 0xffff0000u; return c.f;
}

// zero two buffers in one dispatch (replaces 2x hipMemsetAsync @ 42us each)
__global__ void zero2_kernel(int* __restrict__ a, int na, int* __restrict__ b, int nb) {
  int i = blockIdx.x * blockDim.x + threadIdx.x;
  int stride = gridDim.x * blockDim.x;
  for (int j = i; j < na; j += stride) a[j] = 0;
  for (int j = i; j < nb; j += stride) b[j] = 0;
}

// ---------------------------------------------------------------------------
// graph preprocessing: degrees + per-edge rank, norm, CSR-by-dst
// ---------------------------------------------------------------------------
__global__ void count_rank_kernel(const int* __restrict__ dst, int E,
                                  int* __restrict__ deg, int* __restrict__ rank) {
  int i = blockIdx.x * blockDim.x + threadIdx.x;
  if (i < E) rank[i] = atomicAdd(&deg[dst[i]], 1);
}

__global__ void dinv_kernel(const int* __restrict__ deg, int n, float* __restrict__ dinv) {
  int i = blockIdx.x * blockDim.x + threadIdx.x;
  if (i < n) dinv[i] = 1.0f / sqrtf((float)(deg[i] + 1));  // +1 self-loop
}

// block-wise exclusive scan; also emits per-block total
__global__ void scan_block_kernel(const int* __restrict__ in, int n,
                                  int* __restrict__ out_excl, int* __restrict__ bsum) {
  __shared__ int sh[TPB];
  int t = threadIdx.x;
  int i = blockIdx.x * TPB + t;
  int v = (i < n) ? in[i] : 0;
  sh[t] = v;
  __syncthreads();
  for (int off = 1; off < TPB; off <<= 1) {
    int x = (t >= off) ? sh[t - off] : 0;
    __syncthreads();
    sh[t] += x;
    __syncthreads();
  }
  if (i < n) out_excl[i] = sh[t] - v;          // exclusive
  if (t == TPB - 1 && bsum != nullptr) bsum[blockIdx.x] = sh[t];
}

__global__ void scan_fixup_kernel(int* __restrict__ rs, const int* __restrict__ boff,
                                  int n, int total) {
  int i = blockIdx.x * TPB + threadIdx.x;
  if (i < n) rs[i] += boff[blockIdx.x];
  else if (i == n) rs[n] = total;
}

// atomic-free placement: col[rs[d] + rank[i]] = src[i]
__global__ void fill_kernel(const int* __restrict__ src, const int* __restrict__ dst,
                            const int* __restrict__ rank, const int* __restrict__ rs,
                            int E, int* __restrict__ col) {
  int i = blockIdx.x * blockDim.x + threadIdx.x;
  if (i < E) {
    int d = dst[i];
    col[rs[d] + rank[i]] = src[i];
  }
}

// ---------------------------------------------------------------------------
// GEMM: zws[N,128](bf16) = dinv[r] * (A[N,128](f32) @ W[128,128](f32))
// ---------------------------------------------------------------------------
__global__ __launch_bounds__(256) void gemm128_kernel(const float* __restrict__ A,
                                                      const float* __restrict__ W,
                                                      const float* __restrict__ dinv,
                                                      ushort16* __restrict__ out, int nrows) {
  __shared__ float Wl[128 * 128];   // 64 KB
  __shared__ float Al[32][128];     // 16 KB
  int t = threadIdx.x;
  {
    const float4* __restrict__ W4 = (const float4*)W;
    float4* Wl4 = (float4*)Wl;
#pragma unroll
    for (int i = 0; i < 16; ++i) Wl4[t + 256 * i] = W4[t + 256 * i];
  }
  int r0 = blockIdx.x * 32;
  {
    const float4* __restrict__ A4 = (const float4*)A;
#pragma unroll
    for (int i = 0; i < 4; ++i) {
      int idx = t + 256 * i;        // 0..1023
      int r = idx >> 5;             // 0..31
      int cc = idx & 31;            // float4 index within row
      float4 v = make_float4(0.f, 0.f, 0.f, 0.f);
      if (r0 + r < nrows) v = A4[(size_t)(r0 + r) * 32 + cc];
      *(float4*)&Al[r][cc * 4] = v;
    }
  }
  __syncthreads();

  int c4 = (t & 31) * 4;            // output cols c4..c4+3
  int rg = (t >> 5) * 4;            // output rows rg..rg+3 (local)
  float4 acc0 = {0, 0, 0, 0}, acc1 = {0, 0, 0, 0}, acc2 = {0, 0, 0, 0}, acc3 = {0, 0, 0, 0};
#pragma unroll 8
  for (int k = 0; k < 128; ++k) {
    float4 w = *(const float4*)&Wl[k * 128 + c4];
    float a0 = Al[rg + 0][k];
    float a1 = Al[rg + 1][k];
    float a2 = Al[rg + 2][k];
    float a3 = Al[rg + 3][k];
    acc0.x += w.x * a0; acc0.y += w.y * a0; acc0.z += w.z * a0; acc0.w += w.w * a0;
    acc1.x += w.x * a1; acc1.y += w.y * a1; acc1.z += w.z * a1; acc1.w += w.w * a1;
    acc2.x += w.x * a2; acc2.y += w.y * a2; acc2.z += w.z * a2; acc2.w += w.w * a2;
    acc3.x += w.x * a3; acc3.y += w.y * a3; acc3.z += w.z * a3; acc3.w += w.w * a3;
  }
  int r = r0 + rg;
#pragma unroll
  for (int rr = 0; rr < 4; ++rr) {
    float4 acc = (rr == 0) ? acc0 : (rr == 1) ? acc1 : (rr == 2) ? acc2 : acc3;
    if (r + rr < nrows) {
      float di = dinv[r + rr];
      ushort4 p;
      p.x = f2bf(di * acc.x); p.y = f2bf(di * acc.y);
      p.z = f2bf(di * acc.z); p.w = f2bf(di * acc.w);
      *(ushort4*)&out[(size_t)(r + rr) * 128 + c4] = p;
    }
  }
}

// ---------------------------------------------------------------------------
// aggregation: out[n] = prelu( dinv[n]*( zws[n] + sum_{e: dst=n} zws[col[e]] ) + b )
// one wave per node. Wave-cooperative col staging: one coalesced load of up to
// 64 indices, broadcast via __shfl (readlane) -> all gathers independent.
// ---------------------------------------------------------------------------
__global__ __launch_bounds__(256) void aggregate_kernel(
    const ushort16* __restrict__ zws, const int* __restrict__ rs,
    const int* __restrict__ col,
    const float* __restrict__ dinv, const float* __restrict__ bias,
    const float* __restrict__ alpha, float* __restrict__ out, int nrows) {
  int wid = threadIdx.x >> 6;
  int lane = threadIdx.x & 63;
  int node = blockIdx.x * 4 + wid;
  if (node >= nrows) return;
  int c = lane * 2;

  uint32 pv = *(const uint32*)&zws[(size_t)node * 128 + c];
  float accx = bflo(pv), accy = bfhi(pv);

  int e0 = rs[node], e1 = rs[node + 1];
  for (int base = e0; base < e1; base += 64) {
    int nb = e1 - base; if (nb > 64) nb = 64;
    int colv = (base + lane < e1) ? col[base + lane] : 0;   // one coalesced load
    int j = 0;
    for (; j + 8 <= nb; j += 8) {
      int s0 = __shfl(colv, j + 0);
      int s1 = __shfl(colv, j + 1);
      int s2 = __shfl(colv, j + 2);
      int s3 = __shfl(colv, j + 3);
      int s4 = __shfl(colv, j + 4);
      int s5 = __shfl(colv, j + 5);
      int s6 = __shfl(colv, j + 6);
      int s7 = __shfl(colv, j + 7);
      uint32 p0 = *(const uint32*)&zws[(size_t)s0 * 128 + c];
      uint32 p1 = *(const uint32*)&zws[(size_t)s1 * 128 + c];
      uint32 p2 = *(const uint32*)&zws[(size_t)s2 * 128 + c];
      uint32 p3 = *(const uint32*)&zws[(size_t)s3 * 128 + c];
      uint32 p4 = *(const uint32*)&zws[(size_t)s4 * 128 + c];
      uint32 p5 = *(const uint32*)&zws[(size_t)s5 * 128 + c];
      uint32 p6 = *(const uint32*)&zws[(size_t)s6 * 128 + c];
      uint32 p7 = *(const uint32*)&zws[(size_t)s7 * 128 + c];
      accx += bflo(p0) + bflo(p1) + bflo(p2) + bflo(p3)
            + bflo(p4) + bflo(p5) + bflo(p6) + bflo(p7);
      accy += bfhi(p0) + bfhi(p1) + bfhi(p2) + bfhi(p3)
            + bfhi(p4) + bfhi(p5) + bfhi(p6) + bfhi(p7);
    }
    for (; j < nb; ++j) {
      int s = __shfl(colv, j);
      uint32 p = *(const uint32*)&zws[(size_t)s * 128 + c];
      accx += bflo(p);
      accy += bfhi(p);
    }
  }

  float di = dinv[node];
  float2 b = *(const float2*)&bias[c];
  float2 al = *(const float2*)&alpha[c];
  float zx = di * accx + b.x, zy = di * accy + b.y;
  zx = zx > 0.f ? zx : al.x * zx;
  zy = zy > 0.f ? zy : al.y * zy;
  float2 r; r.x = zx; r.y = zy;
  *(float2*)&out[(size_t)node * 128 + c] = r;
}

// ---------------------------------------------------------------------------
// pooling: g[gi] = [ sum_{batch[n]==gi} z1[n] | sum z2[n] ]  (batch sorted)
// chunked over nodes: block = PROWS rows, running segmented sum + atomicAdd
// at segment boundaries. g must be pre-zeroed.
// ---------------------------------------------------------------------------
__global__ __launch_bounds__(256) void pool_kernel(const float* __restrict__ z1,
                                                   const float* __restrict__ z2,
                                                   const int* __restrict__ batch, int n,
                                                   float* __restrict__ g) {
  int r0 = blockIdx.x * PROWS;
  int t = threadIdx.x;
  __shared__ int bsh[PROWS];
  int rmax = n - r0; if (rmax > PROWS) rmax = PROWS;
  if (t < PROWS && t < rmax) bsh[t] = batch[r0 + t];
  __syncthreads();

  int c = t & 127;
  const float* __restrict__ src = (t < 128) ? z1 : z2;
  float acc = 0.f;
  int cur = bsh[0];
  for (int i = 0; i < rmax; ++i) {
    int b = bsh[i];
    if (b != cur) {
      atomicAdd(&g[(size_t)cur * 256 + t], acc);
      acc = 0.f;
      cur = b;
    }
    acc += src[(size_t)(r0 + i) * 128 + c];
  }
  atomicAdd(&g[(size_t)cur * 256 + t], acc);
}

// ---------------------------------------------------------------------------
// launcher
// ---------------------------------------------------------------------------
extern "C" void kernel_launch(void* const* d_in, const int* in_sizes, int n_in,
                              void* d_out, int out_size, void* d_ws, size_t ws_size,
                              hipStream_t stream) {
  const float* x     = (const float*)d_in[0];
  const int*   ei    = (const int*)d_in[1];
  const int*   batch = (const int*)d_in[2];
  const float* W0    = (const float*)d_in[3];
  const float* b0    = (const float*)d_in[4];
  const float* a0    = (const float*)d_in[5];
  const float* W1    = (const float*)d_in[6];
  const float* b1    = (const float*)d_in[7];
  const float* a1    = (const float*)d_in[8];
  float* out = (float*)d_out;

  const int N = in_sizes[0] / 128;
  const int E = in_sizes[1] / 2;
  const int G = (out_size - N * 128) / 256;

  const int* src  = ei;       // edge_index[0]
  const int* dstp = ei + E;   // edge_index[1]

  // workspace layout (4-byte words)
  int* w = (int*)d_ws;
  size_t o = 0;
  int*      deg    = w + o; o += (size_t)N;
  int*      rs     = w + o; o += (size_t)((N + 1 + 3) & ~3);
  int*      bsum   = w + o; o += 256;
  int*      boff   = w + o; o += 256;
  int*      col    = w + o; o += (size_t)E;
  int*      rank   = w + o; o += (size_t)E;
  float*    dinv   = (float*)(w + o); o += (size_t)N;
  ushort16* zws    = (ushort16*)(w + o); o += (size_t)N * 64;   // bf16 [N,128]
  float*    z1     = (float*)(w + o); o += (size_t)N * 128;
  (void)ws_size; (void)n_in;

  const int blkE = (E + TPB - 1) / TPB;
  const int blkN = (N + TPB - 1) / TPB;   // also #scan blocks (<= 256 for N<=65536)

  float* g = out + (size_t)N * 128;

  // zero deg + pooled-output region in one cheap dispatch
  zero2_kernel<<<512, TPB, 0, stream>>>(deg, N, (int*)g, G * 256);

  // degrees + per-edge rank -> dinv
  count_rank_kernel<<<blkE, TPB, 0, stream>>>(dstp, E, deg, rank);
  dinv_kernel<<<blkN, TPB, 0, stream>>>(deg, N, dinv);

  // exclusive scan of deg -> row_start (rs), hierarchical
  scan_block_kernel<<<blkN, TPB, 0, stream>>>(deg, N, rs, bsum);
  scan_block_kernel<<<1, TPB, 0, stream>>>(bsum, blkN, boff, nullptr);
  scan_fixup_kernel<<<(N + TPB) / TPB, TPB, 0, stream>>>(rs, boff, N, E);

  // CSR fill (atomic-free)
  fill_kernel<<<blkE, TPB, 0, stream>>>(src, dstp, rank, rs, E, col);

  // layer 0: zws = bf16(dinv * (x @ W0)) ; z1 = prelu(dinv*(zws_self + sum) + b0)
  gemm128_kernel<<<(N + 31) / 32, 256, 0, stream>>>(x, W0, dinv, zws, N);
  aggregate_kernel<<<(N + 3) / 4, 256, 0, stream>>>(zws, rs, col, dinv, b0, a0, z1, N);

  // layer 1
  gemm128_kernel<<<(N + 31) / 32, 256, 0, stream>>>(z1, W1, dinv, zws, N);
  aggregate_kernel<<<(N + 3) / 4, 256, 0, stream>>>(zws, rs, col, dinv, b1, a1, out, N);

  // pooling -> g
  pool_kernel<<<(N + PROWS - 1) / PROWS, 256, 0, stream>>>(z1, out, batch, N, g);
}